// Round 5
// baseline (578.772 us; speedup 1.0000x reference)
//
#include <hip/hip_runtime.h>
#include <hip/hip_bf16.h>
#include <stdint.h>

// Mahalanobis loss via Gram reformulation:
//   mean_n (f_n-mu)^T C (f_n-mu)
//     = (1/N)[ <C, G> - sum_{d,e} C_de (coef_d mu_e + mu_d coef_e) ],
//   G = Fb^T Fb (bf16, fp32 accum), s = sum_n fb_n, coef = s - (N/2) mu.
//
// R8: R6/R7 nulls re-examined: prep (not gram) is the likely pig. Old prep
// read F in 256-B windows of 2-KB rows (DRAM page efficiency ~25-50% ->
// ~190-210us inferred), masking gram's improvement. New prep: block = 64
// full rows (reads full 2-KB rows, L1-covered 16B/lane sweeps), register
// 4x4 transpose, DIRECT b64 global stores in 128-B contiguous runs to the
// tiled/swizzled Ft image (no LDS transpose at all). Image formula is
// bit-identical to R7 (j = n ^ ((d&7)<<3), base (p*2048+m)<<13) so gram is
// byte-compatible and UNCHANGED. s moves to per-block partials sp[d][m]
// (no atomics), reduced by tiny sred kernel (also zeroes out; zero kernel
// deleted). Prediction: prep ~75us; total ~390 (gram~60) or ~490 (gram~160)
// -- either disambiguates gram's true cost.

typedef __attribute__((ext_vector_type(8))) short short8;
typedef __attribute__((ext_vector_type(4))) short short4v;
typedef __attribute__((ext_vector_type(4))) float floatx4;

static constexpr int NROWS = 131072;
static constexpr int DDIM  = 512;

__device__ __forceinline__ short f2bf(float f) {
  __bf16 b = (__bf16)f;                   // RNE f32->bf16
  return __builtin_bit_cast(short, b);
}
__device__ __forceinline__ float bf2f(short s) {
  __bf16 b = __builtin_bit_cast(__bf16, s);
  return (float)b;
}

__device__ __forceinline__ void gld16(const void* g, void* l) {
  __builtin_amdgcn_global_load_lds(
      (const __attribute__((address_space(1))) void*)g,
      (__attribute__((address_space(3))) void*)l, 16, 0, 0);
}

// ---- pre-pass: F[n][d] f32 -> tiled/swizzled Ft blocks + sp[d][m] ----
// Ft block B[p][m] (16 KB): row r (0..127) at shorts [r*64,+64); short j of
// row r holds n = 64m + (j ^ ((r&7)<<3)), d = 128p + r.   (== R7's image)
// Prep block m: rows [64m, 64m+64), ALL 512 d. Grid 2048 x 256 threads.
__global__ __launch_bounds__(256) void maha_prep(const float* __restrict__ F,
                                                 short* __restrict__ Ft,
                                                 float* __restrict__ sp) {
  __shared__ float Lr[512 * 17 + 16];     // s-partials, pad-17 (4-way max)
  const int m = blockIdx.x;
  const int n0 = m * 64;
  const int t = threadIdx.x;
  const int nq = t & 15;                  // n-quad: rows 4*nq..+4
  const int dq = t >> 4;                  // d-window: cols 32*dq..+32

  const float* fb = F + (size_t)(n0 + 4 * nq) * DDIM + 32 * dq;

#pragma unroll
  for (int db = 0; db < 8; db++) {        // 4-col steps within the d-window
    floatx4 v[4];
#pragma unroll
    for (int nn = 0; nn < 4; nn++)
      v[nn] = *(const floatx4*)(fb + (size_t)nn * DDIM + 4 * db);
#pragma unroll
    for (int dd = 0; dd < 4; dd++) {
      const int d = 32 * dq + 4 * db + dd;
      short4v pk;                         // register 4x4 transpose: column dd
      float ssum = 0.f;
#pragma unroll
      for (int nn = 0; nn < 4; nn++) {
        pk[nn] = f2bf(v[nn][dd]);
        ssum += bf2f(pk[nn]);
      }
      const int p = d >> 7, r = d & 127;
      const int j = (4 * nq) ^ ((d & 7) << 3);  // XOR bits>=3: 4-runs intact
      *(short4v*)&Ft[(((size_t)p * 2048 + m) << 13) + r * 64 + j] = pk;
      Lr[d * 17 + nq] = ssum;             // complete after this (db,dd)
    }
  }
  __syncthreads();
  // reduce 16 nq-partials per d; thread t owns d = 2t, 2t+1
#pragma unroll
  for (int k = 0; k < 2; k++) {
    const int d = 2 * t + k;
    float s = 0.f;
#pragma unroll
    for (int i = 0; i < 16; i++) s += Lr[d * 17 + i];
    sp[(size_t)d * 2048 + m] = s;         // d-major: sred reads contiguous
  }
}

// ---- s-reduce: s_ws[d] = sum_m sp[d][m]; also zero out ----
__global__ __launch_bounds__(256) void maha_sred(const float* __restrict__ sp,
                                                 float* __restrict__ s_ws,
                                                 float* __restrict__ out) {
  const int b = blockIdx.x;               // 8 blocks x 64 d
  const int t = threadIdx.x;
  const int d = 64 * b + (t >> 2), part = t & 3;
  const float* pp = sp + (size_t)d * 2048 + part * 512;
  float s = 0.f;
#pragma unroll
  for (int i = 0; i < 128; i++) {
    floatx4 v = *(const floatx4*)(pp + 4 * i);
    s += v[0] + v[1] + v[2] + v[3];
  }
  s += __shfl_down(s, 1);
  s += __shfl_down(s, 2);
  if (part == 0) s_ws[d] = s;
  if (b == 0 && t == 0) out[0] = 0.0f;
}

// ---- main: symmetric Gram tiles from tiled Ft, fused <C,G> epilogue ----
// (byte-identical to R7's gram)
__global__ __launch_bounds__(512, 2) void maha_gram(const short* __restrict__ Ft,
                                                    const float* __restrict__ C,
                                                    float* __restrict__ out) {
  __shared__ short ABs[32768];
  __shared__ float red[8];

  static const int TI[10] = {0,0,0,0,1,1,1,2,2,3};
  static const int TJ[10] = {0,1,2,3,1,2,3,2,3,3};

  const int bid  = blockIdx.x;
  const int gg   = bid / 80;
  const int rr   = bid % 80;
  const int slab = gg * 8 + (rr & 7);     // 0..127, 1024 K-rows each
  const int tile = rr >> 3;               // 0..9
  const int ti = TI[tile], tj = TJ[tile];
  const bool diag = (ti == tj);

  const int th = threadIdx.x;
  const int wave = th >> 6, lane = th & 63;

  const char* FtB = (const char*)Ft;
  const int woff = wave * 1024;               // wave-uniform LDS offset
  const int goff = woff + lane * 16;          // per-lane global offset
  char* lABs = (char*)ABs;

  auto issue = [&](int c) {               // 4 loads/wave (2 if diag)
    const size_t m = (size_t)slab * 16 + c;
    const char* blkA = FtB + (((size_t)ti * 2048 + m) << 14);
    char* lbase = lABs + (c & 1) * 16384;
    gld16(blkA + goff, lbase + woff);
    gld16(blkA + 8192 + goff, lbase + 8192 + woff);
    if (!diag) {
      const char* blkB = FtB + (((size_t)tj * 2048 + m) << 14);
      gld16(blkB + goff, lbase + 32768 + woff);
      gld16(blkB + 8192 + goff, lbase + 32768 + 8192 + woff);
    }
  };

  const int wk = wave & 1;                // K-half of the 64-row chunk
  const int wm = (wave >> 1) & 1;
  const int wn = wave >> 2;
  const int l15 = lane & 15, quad = lane >> 4;
  const int kb = wk * 64 + quad * 16;     // byte offset of this lane's K-slice

  int idxA[4], idxB[4];
#pragma unroll
  for (int mi = 0; mi < 4; mi++) {
    const int r = wm * 64 + mi * 16 + l15;
    idxA[mi] = r * 64 + ((kb ^ ((r & 7) << 4)) >> 1);
    const int e = wn * 64 + mi * 16 + l15;
    idxB[mi] = e * 64 + ((kb ^ ((e & 7) << 4)) >> 1);
  }
  const int bbase = diag ? 0 : 16384;     // diag reads B from the A buffer

  floatx4 acc[4][4];
#pragma unroll
  for (int i = 0; i < 4; i++)
#pragma unroll
    for (int j = 0; j < 4; j++) acc[i][j] = floatx4{0.f, 0.f, 0.f, 0.f};

  issue(0);
  issue(1);

#pragma unroll 2
  for (int c = 0; c < 16; ++c) {
    if (c == 15)      asm volatile("s_waitcnt vmcnt(0)" ::: "memory");
    else if (diag)    asm volatile("s_waitcnt vmcnt(2)" ::: "memory");
    else              asm volatile("s_waitcnt vmcnt(4)" ::: "memory");
    __builtin_amdgcn_s_barrier();         // slot c fully staged for all waves
    const int sb = (c & 1) * 8192;
    short8 af[4], bf[4];
#pragma unroll
    for (int mi = 0; mi < 4; mi++) af[mi] = *(const short8*)&ABs[sb + idxA[mi]];
#pragma unroll
    for (int fj = 0; fj < 4; fj++) bf[fj] = *(const short8*)&ABs[bbase + sb + idxB[fj]];
    asm volatile("s_waitcnt lgkmcnt(0)" ::: "memory");  // my slot-c reads retired
    __builtin_amdgcn_s_barrier();         // all waves done reading slot c
    if (c < 14) issue(c + 2);             // overwrite slot c; overlaps MFMA
    __builtin_amdgcn_s_setprio(1);
#pragma unroll
    for (int fj = 0; fj < 4; fj++)
#pragma unroll
      for (int mi = 0; mi < 4; mi++)
        acc[mi][fj] = __builtin_amdgcn_mfma_f32_16x16x32_bf16(
            af[mi], bf[fj], acc[mi][fj], 0, 0, 0);
    __builtin_amdgcn_s_setprio(0);
  }

  // ---- epilogue: psum = sum W_de * G_de, W = C_ij (+ C_ji^T if offdiag) ----
  const int d0 = ti * 128, e0 = tj * 128;
  float psum = 0.f;
#pragma unroll
  for (int mi = 0; mi < 4; mi++) {
#pragma unroll
    for (int fj = 0; fj < 4; fj++) {
      const int dg = d0 + wm * 64 + mi * 16 + quad * 4;
      const int eg = e0 + wn * 64 + fj * 16 + l15;
#pragma unroll
      for (int r2 = 0; r2 < 4; r2++) {
        float wgt = C[(size_t)(dg + r2) * DDIM + eg];
        if (!diag) wgt += C[(size_t)eg * DDIM + dg + r2];
        psum += wgt * acc[mi][fj][r2];
      }
    }
  }

#pragma unroll
  for (int off = 32; off > 0; off >>= 1) psum += __shfl_down(psum, off);
  if (lane == 0) red[wave] = psum;
  __syncthreads();
  if (th == 0) {
    const float tot = red[0] + red[1] + red[2] + red[3] +
                      red[4] + red[5] + red[6] + red[7];
    atomicAdd(out, tot * (1.0f / (float)NROWS));
  }
}

// ---- correction: out += -(1/N) sum_{d,e} C_de (coef_d mu_e + mu_d coef_e) ----
__global__ __launch_bounds__(256) void maha_corr(const float* __restrict__ C,
                                                 const float* __restrict__ mu,
                                                 const float* __restrict__ s_ws,
                                                 float* __restrict__ out) {
  __shared__ float red[4];
  const int b = blockIdx.x;               // 128 blocks x 4 d-rows
  const int th = threadIdx.x;
  float cd[4], md[4];
#pragma unroll
  for (int dd = 0; dd < 4; dd++) {
    const int d = b * 4 + dd;
    md[dd] = mu[d];
    cd[dd] = s_ws[d] - 0.5f * (float)NROWS * md[dd];
  }
  float p = 0.f;
#pragma unroll
  for (int rep = 0; rep < 2; rep++) {
    const int e = th + rep * 256;
    const float me = mu[e];
    const float ce = s_ws[e] - 0.5f * (float)NROWS * me;
#pragma unroll
    for (int dd = 0; dd < 4; dd++)
      p += C[(size_t)(b * 4 + dd) * DDIM + e] * (cd[dd] * me + md[dd] * ce);
  }
  const int lane = th & 63, wave = th >> 6;
#pragma unroll
  for (int off = 32; off > 0; off >>= 1) p += __shfl_down(p, off);
  if (lane == 0) red[wave] = p;
  __syncthreads();
  if (th == 0)
    atomicAdd(out, -(red[0] + red[1] + red[2] + red[3]) * (1.0f / (float)NROWS));
}

extern "C" void kernel_launch(void* const* d_in, const int* in_sizes, int n_in,
                              void* d_out, int out_size, void* d_ws, size_t ws_size,
                              hipStream_t stream) {
  const float* feature = (const float*)d_in[0];   // [131072, 512] fp32
  const float* mean    = (const float*)d_in[1];   // [512] fp32
  const float* invcov  = (const float*)d_in[2];   // [512, 512] fp32
  float* out = (float*)d_out;                     // scalar fp32
  float* s_ws = (float*)d_ws;                     // s[512] fp32 (2 KB)
  float* sp   = (float*)((char*)d_ws + 4096);     // sp[512][2048] f32 (4 MB)
  short* Ft   = (short*)((char*)d_ws + 4096 + (size_t)4 * 1024 * 1024);

  maha_prep<<<2048, 256, 0, stream>>>(feature, Ft, sp);
  maha_sred<<<8, 256, 0, stream>>>(sp, s_ws, out);
  maha_gram<<<1280, 512, 0, stream>>>(Ft, invcov, out);
  maha_corr<<<128, 256, 0, stream>>>(invcov, mean, s_ws, out);
}

// Round 6
// 443.695 us; speedup vs baseline: 1.3044x; 1.3044x over previous
//
#include <hip/hip_runtime.h>
#include <hip/hip_bf16.h>
#include <stdint.h>

// Mahalanobis loss via Gram reformulation:
//   mean_n (f_n-mu)^T C (f_n-mu)
//     = (1/N)[ <C, G> - sum_{d,e} C_de (coef_d mu_e + mu_d coef_e) ],
//   G = Fb^T Fb (bf16, fp32 accum), s = sum_n fb_n, coef = s - (N/2) mu.
//
// R9: ledger across R5-R8 shows gram ~155us REGARDLESS of staging style
// (reg-staged 1.3GB / gld_lds 655MB / tiled-swizzled 557MB all equal), i.e.
// cost = #barrier-iters x ~4800cy (DS pipe + staging + skew), NOT HBM bytes;
// R5 also proved F reads run at 8.3TB/s effective (L3). The two-pass Ft
// detour (prep measured 164us, 45% HBM, 1.56x over-fetch) is strictly worse
// than restructuring gram itself. This round: ONE pass, 256x256 super-tiles:
// 3 tiles x 128 slabs = 384 blocks -> 32 serial iter-slots/CU (vs 40) and
// 2.5x fewer staged bytes per output. 8 waves = 2x4 grid, acc[8][4] (128
// VGPR); reg budget engineered ~248<=256 (8-wave residency): v[4][4] stage
// 64 + frags 32 (sub-batched af[4]) + addr (frag addrs collapse to base +
// i*1024 immediates; swizzle (l15&7)<<3 is mi/fj-invariant). LDS 2x64KB
// slots + sred = 139KB, 1 block/CU. R5's proven single-barrier pipeline.
// s-accum back in diag blocks; prep/sred/Ft deleted.

typedef __attribute__((ext_vector_type(8))) short short8;
typedef __attribute__((ext_vector_type(4))) short short4v;
typedef __attribute__((ext_vector_type(4))) float floatx4;

static constexpr int NROWS = 131072;
static constexpr int DDIM  = 512;

__device__ __forceinline__ short f2bf(float f) {
  __bf16 b = (__bf16)f;                   // RNE f32->bf16
  return __builtin_bit_cast(short, b);
}
__device__ __forceinline__ float bf2f(short s) {
  __bf16 b = __builtin_bit_cast(__bf16, s);
  return (float)b;
}

// ---- zero-init: s_ws[512] and out (poisoned 0xAA before every launch) ----
__global__ __launch_bounds__(512) void maha_zero(float* __restrict__ s_ws,
                                                 float* __restrict__ out) {
  s_ws[threadIdx.x] = 0.0f;
  if (threadIdx.x == 0) out[0] = 0.0f;
}

// ---- main: 256x256 symmetric Gram super-tiles, fused <C,G> + s ----
__global__ __launch_bounds__(512, 1) void maha_gram(const float* __restrict__ F,
                                                    const float* __restrict__ C,
                                                    float* __restrict__ s_ws,
                                                    float* __restrict__ out) {
  // slot s at shorts [s*32768,+32768): A [0,16384), B [16384,32768).
  // Image per 128-row sub-block: row r shorts [r*64,+64); short j of row r
  // holds n = j ^ ((r&7)<<3)  (r = full 0..255 row index).
  __shared__ short ABs[65536];            // 128 KB
  __shared__ float sred[2048];            // diag s-partials [r][nqb]
  __shared__ float red[8];

  static const int TI2[3] = {0, 0, 1};    // heavy (0,1) first in each window
  static const int TJ2[3] = {1, 0, 1};

  const int bid  = blockIdx.x;
  const int gg   = bid / 24;
  const int rr   = bid % 24;
  const int slab = gg * 8 + (rr & 7);     // 0..127, 1024 K-rows each
  const int tile = rr >> 3;               // 0..2
  const int ti = TI2[tile], tj = TJ2[tile];
  const bool diag = (ti == tj);

  const int th = threadIdx.x;
  const int wave = th >> 6, lane = th & 63;

  // ---- staging mapping: 256 threads per matrix (A: waves 0-3, B: 4-7) ----
  const int half = th >> 8;
  const int w4   = wave & 3;
  const int dqb  = 8 * w4 + (lane >> 3);  // d-quad base 0..31
  const int nqb  = lane & 7;              // n-quad base 0..7
  const int colbase = 256 * (half ? tj : ti);
  const bool skipstage = diag && (half == 1);
  const bool sacc = diag && (half == 0);
  short* mybuf = ABs + half * 16384;

  const float* gbase = F + (size_t)slab * 1024 * DDIM + colbase;

  floatx4 v[4][4];                        // one chunk staged in regs (64 VGPR)
  float s_part[2][4] = {{0.f,0.f,0.f,0.f},{0.f,0.f,0.f,0.f}};

  auto loadG = [&](int c) {
    if (skipstage) return;
#pragma unroll
    for (int k = 0; k < 4; k++) {
      const int dq = dqb + 32 * (k & 1);
      const int nq = nqb + 8 * (k >> 1);
      const float* p = gbase + (size_t)(c * 64 + 4 * nq) * DDIM + 4 * dq;
#pragma unroll
      for (int nn = 0; nn < 4; nn++)
        v[k][nn] = *(const floatx4*)(p + nn * DDIM);
    }
  };

  auto cvtwrite = [&](int slot) {
    if (skipstage) return;
#pragma unroll
    for (int k = 0; k < 4; k++) {
      const int k1 = k & 1;
      const int nq4 = 4 * (nqb + 8 * (k >> 1));
#pragma unroll
      for (int dd = 0; dd < 4; dd++) {
        const int rl = 4 * dqb + dd;      // row within 128-sub-block
        short4v pk;                        // register 4x4 transpose
        pk[0] = f2bf(v[k][0][dd]); pk[1] = f2bf(v[k][1][dd]);
        pk[2] = f2bf(v[k][2][dd]); pk[3] = f2bf(v[k][3][dd]);
        if (sacc)
          s_part[k1][dd] += bf2f(pk[0]) + bf2f(pk[1]) + bf2f(pk[2]) + bf2f(pk[3]);
        const int nrun = nq4 ^ ((rl & 7) << 3);
        *(short4v*)&mybuf[slot * 32768 + k1 * 8192 + rl * 64 + nrun] = pk;
      }
    }
  };

  // ---- MFMA mapping: 2x4 spatial wave grid over the 256x256 tile ----
  const int wm = wave >> 2, wn = wave & 3;
  const int l15 = lane & 15, quad = lane >> 4;
  const int swz = (l15 & 7) << 3;         // mi/fj-invariant read swizzle
  const int abase = wm * 8192 + l15 * 64;
  const int bb = (diag ? 0 : 16384) + wn * 4096 + l15 * 64;

  floatx4 acc[8][4];
#pragma unroll
  for (int i = 0; i < 8; i++)
#pragma unroll
    for (int j = 0; j < 4; j++) acc[i][j] = floatx4{0.f, 0.f, 0.f, 0.f};

  loadG(0);
  cvtwrite(0);
  loadG(1);

#pragma unroll 1
  for (int c = 0; c < 16; ++c) {
    __syncthreads();                      // publishes slot c; drains writes
    const int sb = (c & 1) * 32768;
    if (c < 15) cvtwrite(c + 1);          // other slot (read-retired via MFMA)
    if (c < 14) loadG(c + 2);             // issues after v consumed by cvt
#pragma unroll
    for (int ks = 0; ks < 2; ks++) {
      const int kq = ks * 32 + quad * 8;
      short8 bfr[4];
#pragma unroll
      for (int fj = 0; fj < 4; fj++)
        bfr[fj] = *(const short8*)&ABs[sb + bb + fj * 1024 + (kq ^ swz)];
#pragma unroll
      for (int mih = 0; mih < 2; mih++) {
        short8 af[4];
#pragma unroll
        for (int m2 = 0; m2 < 4; m2++)
          af[m2] = *(const short8*)&ABs[sb + abase + (mih * 4 + m2) * 1024 + (kq ^ swz)];
        __builtin_amdgcn_s_setprio(1);
#pragma unroll
        for (int m2 = 0; m2 < 4; m2++)
#pragma unroll
          for (int fj = 0; fj < 4; fj++)
            acc[mih * 4 + m2][fj] = __builtin_amdgcn_mfma_f32_16x16x32_bf16(
                af[m2], bfr[fj], acc[mih * 4 + m2][fj], 0, 0, 0);
        __builtin_amdgcn_s_setprio(0);
      }
    }
  }

  // ---- epilogue: psum = sum W_de * G_de, W = C_ij (+ C_ji^T if offdiag) ----
  const int d0 = ti * 256, e0 = tj * 256;
  float psum = 0.f;
#pragma unroll
  for (int mi = 0; mi < 8; mi++) {
#pragma unroll
    for (int fj = 0; fj < 4; fj++) {
      const int dg = d0 + wm * 128 + mi * 16 + quad * 4;
      const int eg = e0 + wn * 64 + fj * 16 + l15;
#pragma unroll
      for (int r2 = 0; r2 < 4; r2++) {
        float wgt = C[(size_t)(dg + r2) * DDIM + eg];
        if (!diag) wgt += C[(size_t)eg * DDIM + dg + r2];
        psum += wgt * acc[mi][fj][r2];
      }
    }
  }

#pragma unroll
  for (int off = 32; off > 0; off >>= 1) psum += __shfl_down(psum, off);
  if (lane == 0) red[wave] = psum;
  if (sacc) {                             // park s partials (th < 256 only)
#pragma unroll
    for (int k1 = 0; k1 < 2; k1++)
#pragma unroll
      for (int dd = 0; dd < 4; dd++)
        sred[(4 * (dqb + 32 * k1) + dd) * 8 + nqb] = s_part[k1][dd];
  }
  __syncthreads();
  if (th == 0) {
    const float tot = red[0] + red[1] + red[2] + red[3] +
                      red[4] + red[5] + red[6] + red[7];
    atomicAdd(out, tot * (1.0f / (float)NROWS));
  }
  if (diag && th < 256) {
    float sd = 0.f;
#pragma unroll
    for (int j = 0; j < 8; j++) sd += sred[th * 8 + j];
    atomicAdd(&s_ws[ti * 256 + th], sd);
  }
}

// ---- correction: out += -(1/N) sum_{d,e} C_de (coef_d mu_e + mu_d coef_e) ----
__global__ __launch_bounds__(256) void maha_corr(const float* __restrict__ C,
                                                 const float* __restrict__ mu,
                                                 const float* __restrict__ s_ws,
                                                 float* __restrict__ out) {
  __shared__ float red[4];
  const int b = blockIdx.x;               // 128 blocks x 4 d-rows
  const int th = threadIdx.x;
  float cd[4], md[4];
#pragma unroll
  for (int dd = 0; dd < 4; dd++) {
    const int d = b * 4 + dd;
    md[dd] = mu[d];
    cd[dd] = s_ws[d] - 0.5f * (float)NROWS * md[dd];
  }
  float p = 0.f;
#pragma unroll
  for (int rep = 0; rep < 2; rep++) {
    const int e = th + rep * 256;
    const float me = mu[e];
    const float ce = s_ws[e] - 0.5f * (float)NROWS * me;
#pragma unroll
    for (int dd = 0; dd < 4; dd++)
      p += C[(size_t)(b * 4 + dd) * DDIM + e] * (cd[dd] * me + md[dd] * ce);
  }
  const int lane = th & 63, wave = th >> 6;
#pragma unroll
  for (int off = 32; off > 0; off >>= 1) p += __shfl_down(p, off);
  if (lane == 0) red[wave] = p;
  __syncthreads();
  if (th == 0)
    atomicAdd(out, -(red[0] + red[1] + red[2] + red[3]) * (1.0f / (float)NROWS));
}

extern "C" void kernel_launch(void* const* d_in, const int* in_sizes, int n_in,
                              void* d_out, int out_size, void* d_ws, size_t ws_size,
                              hipStream_t stream) {
  const float* feature = (const float*)d_in[0];   // [131072, 512] fp32
  const float* mean    = (const float*)d_in[1];   // [512] fp32
  const float* invcov  = (const float*)d_in[2];   // [512, 512] fp32
  float* out = (float*)d_out;                     // scalar fp32
  float* s_ws = (float*)d_ws;                     // s[512] fp32 (2 KB)

  maha_zero<<<1, 512, 0, stream>>>(s_ws, out);
  maha_gram<<<384, 512, 0, stream>>>(feature, invcov, s_ws, out);
  maha_corr<<<128, 256, 0, stream>>>(invcov, mean, s_ws, out);
}